// Round 1
// baseline (1249.881 us; speedup 1.0000x reference)
//
#include <hip/hip_runtime.h>
#include <cstdint>
#include <cstddef>

#define KNB 32        // neighbors per node
#define DIM 100       // embedding dim
#define HS_PITCH 104  // padded pitch for hs rows (multiple of 4 -> b128 aligned)
#define XS_PITCH 208  // padded pitch for layer-input rows

// tanh(x) = 1 - 2/(exp(2x)+1); __expf(+-inf) handled correctly -> +-1
__device__ __forceinline__ float fast_tanh(float x) {
    float e = __expf(2.0f * x);
    return 1.0f - 2.0f / (e + 1.0f);
}

// One block (256 threads = 4 waves) per node.
// Phase 1: gather 32 neighbor embedding rows into LDS (h and hs = h*s).
// Phase 2: wave-tiled [32 x 101] @ [101 x 100] matmul; wave owns 8 k's,
//          lane owns 2 d-columns; hs via broadcast ds_read_b128, W1 from
//          global (coalesced, L1-cached). tanh -> q1 dot -> shuffle-reduce.
// Phase 3: 32-wide softmax. Phase 4: msg[d] = sum_k att[k]*h[k][d] -> d_ws.
__global__ __launch_bounds__(256, 4) void attn_kernel(
    const int* __restrict__ nei, const float* __restrict__ wei,
    const float* __restrict__ s_vec, const float* __restrict__ emb,
    const float* __restrict__ W1, const float* __restrict__ b1,
    const float* __restrict__ q1, float* __restrict__ msg_out, int N)
{
    __shared__ __align__(16) float h_s[KNB * DIM];        // 12800 B
    __shared__ __align__(16) float hs_s[KNB * HS_PITCH];  // 13312 B
    __shared__ float s_s[DIM];
    __shared__ int   nei_s[KNB];
    __shared__ float wei_s[KNB];
    __shared__ float score_s[KNB];
    __shared__ float att_s[KNB];

    const int tid = threadIdx.x;
    const int n = blockIdx.x;

    // ---- phase 1a: small per-node loads
    if (tid < KNB) {
        nei_s[tid] = nei[(size_t)n * KNB + tid];
        wei_s[tid] = wei[(size_t)n * KNB + tid];
    }
    if (tid >= 128 && tid < 128 + DIM) {
        s_s[tid - 128] = s_vec[(size_t)n * DIM + (tid - 128)];
    }
    __syncthreads();

    // ---- phase 1b: gather neighbor embeddings (coalesced within rows)
    for (int p = tid; p < KNB * DIM; p += 256) {
        int k = p / DIM;
        int i = p - k * DIM;
        float v = emb[(size_t)nei_s[k] * DIM + i];
        h_s[k * DIM + i] = v;
        hs_s[k * HS_PITCH + i] = v * s_s[i];
    }
    __syncthreads();

    // ---- phase 2: matmul + tanh + score
    const int lane = tid & 63;
    const int kw = (tid >> 6) * 8;               // this wave's k-group
    const int d0 = lane;                          // column 0..63
    const bool hi = (lane < DIM - 64);            // lanes 0..35 own 64..99
    const int d1 = hi ? (64 + lane) : (DIM - 1);  // clamped dup read, masked later
    const float q0v = q1[d0];
    const float q1v = hi ? q1[d1] : 0.0f;

    float acc0[8], acc1[8];
    {
        const float b0 = b1[d0];
        const float bb = b1[d1];
        const float ww0 = W1[DIM * DIM + d0];  // W1 row 100 = wei column
        const float ww1 = W1[DIM * DIM + d1];
        #pragma unroll
        for (int k = 0; k < 8; ++k) {
            float wv = wei_s[kw + k];
            acc0[k] = fmaf(wv, ww0, b0);
            acc1[k] = fmaf(wv, ww1, bb);
        }
    }

    for (int i = 0; i < DIM; i += 4) {
        float w0[4], w1v[4];
        #pragma unroll
        for (int u = 0; u < 4; ++u) {
            w0[u]  = W1[(i + u) * DIM + d0];
            w1v[u] = W1[(i + u) * DIM + d1];
        }
        #pragma unroll
        for (int k = 0; k < 8; ++k) {
            const float4 hv = *(const float4*)&hs_s[(kw + k) * HS_PITCH + i];
            acc0[k] = fmaf(hv.w, w0[3], fmaf(hv.z, w0[2], fmaf(hv.y, w0[1], fmaf(hv.x, w0[0], acc0[k]))));
            acc1[k] = fmaf(hv.w, w1v[3], fmaf(hv.z, w1v[2], fmaf(hv.y, w1v[1], fmaf(hv.x, w1v[0], acc1[k]))));
        }
    }

    #pragma unroll
    for (int k = 0; k < 8; ++k) {
        float part = fast_tanh(acc0[k]) * q0v + fast_tanh(acc1[k]) * q1v;
        #pragma unroll
        for (int off = 32; off > 0; off >>= 1)
            part += __shfl_xor(part, off);
        if (lane == 0) score_s[kw + k] = part;
    }
    __syncthreads();

    // ---- phase 3: softmax over 32 neighbors (no masking, per reference)
    if (tid < KNB) {
        float v = score_s[tid];
        float m = v;
        #pragma unroll
        for (int off = 16; off > 0; off >>= 1) m = fmaxf(m, __shfl_xor(m, off));
        float e = __expf(v - m);
        float ssum = e;
        #pragma unroll
        for (int off = 16; off > 0; off >>= 1) ssum += __shfl_xor(ssum, off);
        att_s[tid] = e / ssum;
    }
    __syncthreads();

    // ---- phase 4: msg = att @ h
    if (tid < DIM) {
        float acc = 0.0f;
        #pragma unroll 8
        for (int k = 0; k < KNB; ++k) acc += att_s[k] * h_s[k * DIM + tid];
        msg_out[(size_t)n * DIM + tid] = acc;
    }
}

// One layer of x = relu([x, msg] @ W2 + b2). 32 rows per block; X rows staged
// in LDS (broadcast b128 reads); W2 streamed from global (coalesced, cached).
// nodes != nullptr => input rows gathered as xin[nodes[n]] (layer 1 from emb).
// Safe for out == xin (layer 2 in-place): each block reads only its own rows
// (staged before any store), and no other block touches them.
__global__ __launch_bounds__(256, 4) void layer_kernel(
    const float* xin, const int* __restrict__ nodes,
    const float* __restrict__ msg, const float* __restrict__ W2,
    const float* __restrict__ b2, float* out, int N)
{
    __shared__ __align__(16) float Xs[32 * XS_PITCH];
    const int tid = threadIdx.x;
    const int n0 = blockIdx.x * 32;

    for (int p = tid; p < 32 * 2 * DIM; p += 256) {
        int r = p / (2 * DIM);
        int c = p - r * (2 * DIM);
        int n = n0 + r;
        float v = 0.0f;
        if (n < N) {
            if (c < DIM) {
                size_t row = (size_t)(nodes ? nodes[n] : n) * DIM;
                v = xin[row + c];
            } else {
                v = msg[(size_t)n * DIM + (c - DIM)];
            }
        }
        Xs[r * XS_PITCH + c] = v;
    }
    __syncthreads();

    const int lane = tid & 63;
    const int r0 = (tid >> 6) * 8;                // this wave's 8 rows
    const int d0 = lane;
    const bool hi = (lane < DIM - 64);
    const int d1 = hi ? (64 + lane) : (DIM - 1);

    float acc0[8], acc1[8];
    {
        const float b0 = b2[d0];
        const float bb = b2[d1];
        #pragma unroll
        for (int k = 0; k < 8; ++k) { acc0[k] = b0; acc1[k] = bb; }
    }

    for (int i = 0; i < 2 * DIM; i += 4) {
        float w0[4], w1v[4];
        #pragma unroll
        for (int u = 0; u < 4; ++u) {
            w0[u]  = W2[(i + u) * DIM + d0];
            w1v[u] = W2[(i + u) * DIM + d1];
        }
        #pragma unroll
        for (int k = 0; k < 8; ++k) {
            const float4 xv = *(const float4*)&Xs[(r0 + k) * XS_PITCH + i];
            acc0[k] = fmaf(xv.w, w0[3], fmaf(xv.z, w0[2], fmaf(xv.y, w0[1], fmaf(xv.x, w0[0], acc0[k]))));
            acc1[k] = fmaf(xv.w, w1v[3], fmaf(xv.z, w1v[2], fmaf(xv.y, w1v[1], fmaf(xv.x, w1v[0], acc1[k]))));
        }
    }

    #pragma unroll
    for (int k = 0; k < 8; ++k) {
        int n = n0 + r0 + k;
        if (n < N) {
            out[(size_t)n * DIM + d0] = fmaxf(acc0[k], 0.0f);
            if (hi) out[(size_t)n * DIM + d1] = fmaxf(acc1[k], 0.0f);
        }
    }
}

extern "C" void kernel_launch(void* const* d_in, const int* in_sizes, int n_in,
                              void* d_out, int out_size, void* d_ws, size_t ws_size,
                              hipStream_t stream) {
    const int*   nodes = (const int*)d_in[0];
    const int*   nei   = (const int*)d_in[1];
    const float* wei   = (const float*)d_in[2];
    const float* s_vec = (const float*)d_in[3];
    const float* emb   = (const float*)d_in[4];
    const float* W1    = (const float*)d_in[5];
    const float* b1    = (const float*)d_in[6];
    const float* q1    = (const float*)d_in[7];
    const float* W2    = (const float*)d_in[8];
    const float* b2    = (const float*)d_in[9];
    float* out = (float*)d_out;
    const int N = in_sizes[0];

    float* msg = (float*)d_ws;  // N * DIM floats = 20 MB

    attn_kernel<<<N, 256, 0, stream>>>(nei, wei, s_vec, emb, W1, b1, q1, msg, N);

    const int gB = (N + 31) / 32;
    // layer 1: emb[nodes] -> d_out ; layer 2: d_out -> d_out (row-local, safe)
    layer_kernel<<<gB, 256, 0, stream>>>(emb, nodes, msg, W2, b2, out, N);
    layer_kernel<<<gB, 256, 0, stream>>>(out, nullptr, msg, W2, b2, out, N);
}

// Round 2
// 736.588 us; speedup vs baseline: 1.6969x; 1.6969x over previous
//
#include <hip/hip_runtime.h>
#include <cstdint>
#include <cstddef>

// ---------------- common helpers ----------------

typedef __attribute__((ext_vector_type(8))) short bf16x8;   // 4 VGPRs: MFMA A/B frag
typedef __attribute__((ext_vector_type(16))) float f32x16;  // 16 VGPRs: MFMA C/D

__device__ __forceinline__ unsigned short f2bf(float f) {   // fp32 -> bf16 RNE
    unsigned int u = __builtin_bit_cast(unsigned int, f);
    u += 0x7fffu + ((u >> 16) & 1u);
    return (unsigned short)(u >> 16);
}

template<int CTRL>
__device__ __forceinline__ float dpp_add(float v) {
    int t = __builtin_amdgcn_update_dpp(0, __builtin_bit_cast(int, v), CTRL, 0xf, 0xf, true);
    return v + __builtin_bit_cast(float, t);
}
// DPP ctrl: row_shr:1=0x111 :2=0x112 :4=0x114 :8=0x118 ; row_bcast15=0x142 ; row_ror:8=0x128

__device__ __forceinline__ float fast_tanh(float x) {
    float e = __expf(2.0f * x);
    return 1.0f - 2.0f / (e + 1.0f);
}

// ---------------- prep: W1t[128][128], W2t[128][208] bf16, [n][k] layout ----------------
// W1t rows n>=100 and cols k>=100 are zero (k=100 wei-row folded into acc init).
// W2t rows n>=100 and cols k>=200 are zero.
__global__ void prep_kernel(const float* __restrict__ W1, const float* __restrict__ W2,
                            unsigned short* __restrict__ W1t, unsigned short* __restrict__ W2t)
{
    int idx = blockIdx.x * 256 + threadIdx.x;
    if (idx < 128 * 128) {
        int nn = idx >> 7, kk = idx & 127;
        W1t[idx] = (nn < 100 && kk < 100) ? f2bf(W1[kk * 100 + nn]) : (unsigned short)0;
    } else {
        int j = idx - 128 * 128;
        if (j < 128 * 208) {
            int nn = j / 208, kk = j - nn * 208;
            W2t[j] = (nn < 100 && kk < 200) ? f2bf(W2[kk * 100 + nn]) : (unsigned short)0;
        }
    }
}

// ---------------- attention kernel ----------------
// One block = 4 waves; grid-stride over nodes; wave w owns output n-tile [32w, 32w+32).
// Score matmul S[32,100] = feat[32,101] @ W1[101,100] via mfma_f32_32x32x16_bf16:
//   A[m][k] : lane m=L&31, k=(L>>5)*8+j   (hs rows in LDS, bf16, K padded to 112)
//   B[k][n] : lane n=L&31, k=(L>>5)*8+j   (W1t fragments, persistent in VGPRs)
//   C/D     : col=L&31, row=(reg&3)+8*(reg>>2)+4*(L>>5)
// wei column (k=100) + bias folded into the fp32 accumulator init.
#define HPITCH 104    // h rows (bf16), d padded 100->104 with zeros
#define HSPITCH 120   // hs rows (bf16), k padded 100->112 with zeros (120 for bank spread)
#define P2PITCH 108   // msg partials (fp32)

__global__ __launch_bounds__(256) void attn_kernel(
    const int* __restrict__ nei, const float* __restrict__ wei,
    const float* __restrict__ s_vec, const float* __restrict__ emb,
    const float* __restrict__ W1, const float* __restrict__ b1,
    const float* __restrict__ q1, const unsigned short* __restrict__ W1t,
    float* __restrict__ msg, int N)
{
    __shared__ __align__(16) unsigned short h_s[32 * HPITCH];
    __shared__ __align__(16) unsigned short hs_s[32 * HSPITCH];
    __shared__ __align__(16) float wei_s[32];
    __shared__ __align__(16) float spart[4 * 32];
    __shared__ __align__(16) float att_s[32];
    __shared__ __align__(16) float part2[16 * P2PITCH];

    const int tid  = threadIdx.x;
    const int lane = tid & 63;
    const int w    = tid >> 6;
    const int col  = lane & 31;
    const int hi   = lane >> 5;
    const int n    = w * 32 + col;          // output column 0..127 (>=100 masked)

    // persistent per-lane state (reused across all nodes)
    bf16x8 Bf[7];
    #pragma unroll
    for (int ks = 0; ks < 7; ++ks)
        Bf[ks] = *(const bf16x8*)(W1t + n * 128 + ks * 16 + hi * 8);
    const bool nok  = (n < 100);
    const float b1v  = nok ? b1[n] : 0.0f;
    const float w100 = nok ? W1[100 * 100 + n] : 0.0f;  // W1 row 100 = wei column
    const float q1v  = nok ? q1[n] : 0.0f;

    // zero the pad regions once (never overwritten by staging)
    if (tid < 32) {
        *(uint2*)&hs_s[tid * HSPITCH + 100] = make_uint2(0, 0);       // k 100..103
        *(uint4*)&hs_s[tid * HSPITCH + 104] = make_uint4(0, 0, 0, 0); // k 104..111
        *(uint2*)&h_s[tid * HPITCH + 100]  = make_uint2(0, 0);        // d 100..103
    }
    __syncthreads();

    const int gk = tid >> 3;   // staging: row 0..31
    const int gj = tid & 7;    // staging: float4-lane 0..7

    for (int node = blockIdx.x; node < N; node += gridDim.x) {
        // ---- phase 1: stage wei + gather 32 neighbor rows -> h (bf16), hs = h*s (bf16)
        if (tid < 32) wei_s[tid] = wei[(size_t)node * 32 + tid];
        {
            const int nidx = nei[(size_t)node * 32 + gk];
            const float4* erow = (const float4*)(emb + (size_t)nidx * 100);
            const float4* srow = (const float4*)(s_vec + (size_t)node * 100);
            for (int c4 = gj; c4 < 25; c4 += 8) {
                float4 h4 = erow[c4];
                float4 s4 = srow[c4];
                *(ushort4*)&h_s[gk * HPITCH + c4 * 4] =
                    make_ushort4(f2bf(h4.x), f2bf(h4.y), f2bf(h4.z), f2bf(h4.w));
                *(ushort4*)&hs_s[gk * HSPITCH + c4 * 4] =
                    make_ushort4(f2bf(h4.x * s4.x), f2bf(h4.y * s4.y),
                                 f2bf(h4.z * s4.z), f2bf(h4.w * s4.w));
            }
        }
        __syncthreads();   // B1

        // ---- phase 2: acc init (bias + wei*W1row100) then 7 MFMA k-steps
        f32x16 acc;
        #pragma unroll
        for (int q = 0; q < 4; ++q) {
            float4 wq = *(const float4*)&wei_s[q * 8 + hi * 4];
            acc[q * 4 + 0] = fmaf(wq.x, w100, b1v);
            acc[q * 4 + 1] = fmaf(wq.y, w100, b1v);
            acc[q * 4 + 2] = fmaf(wq.z, w100, b1v);
            acc[q * 4 + 3] = fmaf(wq.w, w100, b1v);
        }
        #pragma unroll
        for (int ks = 0; ks < 7; ++ks) {
            bf16x8 a = *(const bf16x8*)&hs_s[col * HSPITCH + ks * 16 + hi * 8];
            acc = __builtin_amdgcn_mfma_f32_32x32x16_bf16(a, Bf[ks], acc, 0, 0, 0);
        }

        // ---- epilogue: score_part[m] = sum_n tanh(S[m,n])*q1[n] over this wave's 32 n
        float sv[16];
        #pragma unroll
        for (int r = 0; r < 16; ++r) sv[r] = fast_tanh(acc[r]) * q1v;
        #pragma unroll
        for (int r = 0; r < 16; ++r) {
            float v = sv[r];
            v = dpp_add<0x111>(v);  // row_shr:1
            v = dpp_add<0x112>(v);  // row_shr:2
            v = dpp_add<0x114>(v);  // row_shr:4
            v = dpp_add<0x118>(v);  // row_shr:8  -> lane15/31/47/63 hold 16-lane sums
            v = dpp_add<0x142>(v);  // row_bcast15 -> lane31 = sum(0..31), lane63 = sum(32..63)
            sv[r] = v;
        }
        if (col == 31) {           // lanes 31 (hi=0) and 63 (hi=1)
            #pragma unroll
            for (int q = 0; q < 4; ++q)
                *(float4*)&spart[w * 32 + q * 8 + hi * 4] =
                    make_float4(sv[q * 4], sv[q * 4 + 1], sv[q * 4 + 2], sv[q * 4 + 3]);
        }
        __syncthreads();   // B2

        // ---- softmax over 32 neighbors (wave 0; lanes 32-63 mirror lanes 0-31)
        if (w == 0) {
            float s = spart[col] + spart[32 + col] + spart[64 + col] + spart[96 + col];
            float mx = s;
            #pragma unroll
            for (int off = 16; off; off >>= 1) mx = fmaxf(mx, __shfl_xor(mx, off));
            float e = __expf(s - mx);
            float den = e;
            #pragma unroll
            for (int off = 16; off; off >>= 1) den += __shfl_xor(den, off);
            if (lane < 32) att_s[col] = e / den;
        }
        __syncthreads();   // B3

        // ---- phase 4: msg = att @ h. wave w owns k in [8w,8w+8); lane: k=8w+(L>>3), oct=L&7
        {
            const int kl   = lane >> 3;
            const int oct  = lane & 7;
            const int krow = w * 8 + kl;
            const float a  = att_s[krow];
            uint4 r1 = *(const uint4*)&h_s[krow * HPITCH + oct * 8];
            const int oct2 = (oct < 5) ? oct : 4;   // clamped dup read, masked at write
            uint4 r2 = *(const uint4*)&h_s[krow * HPITCH + 64 + oct2 * 8];
            float m1[8], m2[8];
            #define UNP2(u, d0, d1) { d0 = __builtin_bit_cast(float, (u) << 16); \
                                      d1 = __builtin_bit_cast(float, (u) & 0xffff0000u); }
            { float t0,t1; UNP2(r1.x,t0,t1); m1[0]=a*t0; m1[1]=a*t1; }
            { float t0,t1; UNP2(r1.y,t0,t1); m1[2]=a*t0; m1[3]=a*t1; }
            { float t0,t1; UNP2(r1.z,t0,t1); m1[4]=a*t0; m1[5]=a*t1; }
            { float t0,t1; UNP2(r1.w,t0,t1); m1[6]=a*t0; m1[7]=a*t1; }
            { float t0,t1; UNP2(r2.x,t0,t1); m2[0]=a*t0; m2[1]=a*t1; }
            { float t0,t1; UNP2(r2.y,t0,t1); m2[2]=a*t0; m2[3]=a*t1; }
            { float t0,t1; UNP2(r2.z,t0,t1); m2[4]=a*t0; m2[5]=a*t1; }
            { float t0,t1; UNP2(r2.w,t0,t1); m2[6]=a*t0; m2[7]=a*t1; }
            #undef UNP2
            #pragma unroll
            for (int j = 0; j < 8; ++j) {   // row_ror:8 == xor8 pairing (k and k^1)
                m1[j] = dpp_add<0x128>(m1[j]);
                m2[j] = dpp_add<0x128>(m2[j]);
            }
            if ((lane & 8) == 0) {          // one writer per k-pair
                const int slot = w * 4 + (lane >> 4);
                float* p = &part2[slot * P2PITCH];
                *(float4*)&p[oct * 8]     = make_float4(m1[0], m1[1], m1[2], m1[3]);
                *(float4*)&p[oct * 8 + 4] = make_float4(m1[4], m1[5], m1[6], m1[7]);
                if (oct < 5) {
                    *(float4*)&p[64 + oct * 8]     = make_float4(m2[0], m2[1], m2[2], m2[3]);
                    *(float4*)&p[64 + oct * 8 + 4] = make_float4(m2[4], m2[5], m2[6], m2[7]);
                }
            }
        }
        __syncthreads();   // B4

        // ---- stage 3: reduce 16 k-pair partials -> msg (waves 0,1)
        if (w < 2) {
            int d = w * 64 + lane;
            if (d < 100) {
                float s = 0.0f;
                #pragma unroll
                for (int sl = 0; sl < 16; ++sl) s += part2[sl * P2PITCH + d];
                msg[(size_t)node * 100 + d] = s;
            }
        }
        // next iteration's staging touches h_s/hs_s/wei_s only; B1 orders everything else
    }
}

// ---------------- fused 2-layer kernel ----------------
// x = relu([x, msg] @ W2 + b2), twice; layer-1 x = emb[nodes[.]]. 32 rows/block-tile,
// grid-stride; W2t fragments persistent (shared by both layers); layer-1 output
// round-trips through LDS as bf16.
#define XPITCH 216   // 32 rows x [0,100)=x | [100,200)=msg | [200,208)=zero pad

__global__ __launch_bounds__(256) void layer_kernel(
    const int* __restrict__ nodes, const float* __restrict__ emb,
    const float* __restrict__ msg, const float* __restrict__ b2,
    const unsigned short* __restrict__ W2t, float* __restrict__ out, int N)
{
    __shared__ __align__(16) unsigned short Xs[32 * XPITCH];
    const int tid  = threadIdx.x;
    const int lane = tid & 63;
    const int w    = tid >> 6;
    const int col  = lane & 31;
    const int hi   = lane >> 5;
    const int n    = w * 32 + col;

    bf16x8 Bf[13];
    #pragma unroll
    for (int ks = 0; ks < 13; ++ks)
        Bf[ks] = *(const bf16x8*)(W2t + n * 208 + ks * 16 + hi * 8);
    const bool nok = (n < 100);
    const float b2v = nok ? b2[n] : 0.0f;

    if (tid < 32)   // zero pad cols [200,208) once
        *(uint4*)&Xs[tid * XPITCH + 200] = make_uint4(0, 0, 0, 0);

    const int gr = tid >> 3, gj = tid & 7;
    const int ntiles = (N + 31) >> 5;
    for (int t = blockIdx.x; t < ntiles; t += gridDim.x) {
        const int n0 = t * 32;
        __syncthreads();   // B0: prev-iter reads (and first-iter pad) done before staging
        {
            int row = n0 + gr;
            int rc = row < N ? row : N - 1;
            const float4* xr = (const float4*)(emb + (size_t)nodes[rc] * 100);
            const float4* mr = (const float4*)(msg + (size_t)rc * 100);
            for (int c4 = gj; c4 < 25; c4 += 8) {
                float4 v = xr[c4];
                *(ushort4*)&Xs[gr * XPITCH + c4 * 4] =
                    make_ushort4(f2bf(v.x), f2bf(v.y), f2bf(v.z), f2bf(v.w));
                float4 u = mr[c4];
                *(ushort4*)&Xs[gr * XPITCH + 100 + c4 * 4] =
                    make_ushort4(f2bf(u.x), f2bf(u.y), f2bf(u.z), f2bf(u.w));
            }
        }
        __syncthreads();   // B1

        f32x16 acc;
        #pragma unroll
        for (int r = 0; r < 16; ++r) acc[r] = b2v;
        #pragma unroll
        for (int ks = 0; ks < 13; ++ks) {
            bf16x8 a = *(const bf16x8*)&Xs[col * XPITCH + ks * 16 + hi * 8];
            acc = __builtin_amdgcn_mfma_f32_32x32x16_bf16(a, Bf[ks], acc, 0, 0, 0);
        }
        __syncthreads();   // B2: all layer-1 A-reads done before x-cols overwritten
        if (nok) {
            #pragma unroll
            for (int r = 0; r < 16; ++r) {
                int m = (r & 3) + 8 * (r >> 2) + 4 * hi;
                Xs[m * XPITCH + n] = f2bf(fmaxf(acc[r], 0.0f));
            }
        }
        __syncthreads();   // B3

        f32x16 acc2;
        #pragma unroll
        for (int r = 0; r < 16; ++r) acc2[r] = b2v;
        #pragma unroll
        for (int ks = 0; ks < 13; ++ks) {
            bf16x8 a = *(const bf16x8*)&Xs[col * XPITCH + ks * 16 + hi * 8];
            acc2 = __builtin_amdgcn_mfma_f32_32x32x16_bf16(a, Bf[ks], acc2, 0, 0, 0);
        }
        if (nok) {
            #pragma unroll
            for (int r = 0; r < 16; ++r) {
                int m = (r & 3) + 8 * (r >> 2) + 4 * hi;
                int row = n0 + m;
                if (row < N) out[(size_t)row * 100 + n] = fmaxf(acc2[r], 0.0f);
            }
        }
    }
}

// ---------------- launch ----------------
extern "C" void kernel_launch(void* const* d_in, const int* in_sizes, int n_in,
                              void* d_out, int out_size, void* d_ws, size_t ws_size,
                              hipStream_t stream) {
    const int*   nodes = (const int*)d_in[0];
    const int*   nei   = (const int*)d_in[1];
    const float* wei   = (const float*)d_in[2];
    const float* s_vec = (const float*)d_in[3];
    const float* emb   = (const float*)d_in[4];
    const float* W1    = (const float*)d_in[5];
    const float* b1    = (const float*)d_in[6];
    const float* q1    = (const float*)d_in[7];
    const float* W2    = (const float*)d_in[8];
    const float* b2    = (const float*)d_in[9];
    float* out = (float*)d_out;
    const int N = in_sizes[0];

    float* msg = (float*)d_ws;                               // N*100 fp32 = 20 MB
    size_t tail = (ws_size - 98304) & ~(size_t)255;          // weight tables at ws tail
    unsigned short* W1t = (unsigned short*)((char*)d_ws + tail);   // 128*128*2 = 32 KB
    unsigned short* W2t = W1t + 128 * 128;                          // 128*208*2 = 52 KB

    prep_kernel<<<168, 256, 0, stream>>>(W1, W2, W1t, W2t);
    attn_kernel<<<1024, 256, 0, stream>>>(nei, wei, s_vec, emb, W1, b1, q1, W1t, msg, N);
    layer_kernel<<<1024, 256, 0, stream>>>(nodes, emb, msg, b2, W2t, out, N);
}